// Round 11
// baseline (43.667 us; speedup 1.0000x reference)
//
#include <hip/hip_runtime.h>
#include <hip/hip_bf16.h>

#define BB   8
#define CC   128
#define TLEN 8192
#define TBLK 64                      // t per block
#define NB   (BB * (TLEN / TBLK))    // 1024 blocks = 4/CU (32 waves/CU, 100% occ)

typedef __attribute__((ext_vector_type(8))) short short8;
typedef __attribute__((ext_vector_type(4))) float f32x4;

__device__ __forceinline__ short f2bf(float f) {
    union { float f; unsigned u; } v; v.f = f;
    return (short)((v.u + 0x7FFFu + ((v.u >> 16) & 1u)) >> 16);
}
__device__ __forceinline__ float bf2f(unsigned short h) {
    union { unsigned u; float f; } v; v.u = ((unsigned)h) << 16;
    return v.f;
}
// Row swizzle on c-octets: bijective per t-row, preserves 16B frag alignment.
__device__ __forceinline__ int swz(int t, int c) {
    return c ^ (((t ^ (t >> 3)) & 15) << 3);
}

__global__ __launch_bounds__(512, 8)   // 8 waves/EU = 32 waves/CU = 4 blocks/CU
void cfm_fused(const float* __restrict__ x1, const float* __restrict__ tsm,
               const float* __restrict__ z, const float* __restrict__ W,
               const float* __restrict__ blin, const int* __restrict__ xlens,
               const int* __restrict__ plens, float* __restrict__ out)
{
    __shared__ short xt[TBLK][CC];   // bf16 [t][c], swizzled rows (16 KB)
    __shared__ short zt[TBLK][CC];   // 16 KB
    __shared__ float red[8];

    const int bi = blockIdx.x;
    const int b  = bi & 7;
    const int t0 = (bi >> 3) * TBLK;

    const int tid  = threadIdx.x;
    const int lane = tid & 63;
    const int wid  = tid >> 6;          // 0..7 = dtile
    const int r15  = lane & 15;
    const int q4   = lane >> 4;

    const float ts  = tsm[b];
    const int   pl  = plens[b];
    const int   xl  = xlens[b];
    const float oms = 0.999999f;        // 1 - sigma
    const float cz  = 1.0f - oms * ts;
    const float cx  = ts;

    // ---- issue ALL 8 global float4 loads up front (256B/row spans) ----
    const int tj = (tid & 15) * 4;      // t within tile
    const int cr = tid >> 4;            // 0..31; c = cr + p*32
    const size_t gb0 = (size_t)b * CC * TLEN + (size_t)t0 + tj;

    float4 xv[4], zv[4];
    #pragma unroll
    for (int p = 0; p < 4; ++p) {
        xv[p] = *reinterpret_cast<const float4*>(x1 + gb0 + (size_t)(cr + p * 32) * TLEN);
        zv[p] = *reinterpret_cast<const float4*>(z  + gb0 + (size_t)(cr + p * 32) * TLEN);
    }

    // ---- W fragments for this wave's dtile (L2-hot), cvt under load shadow ----
    short8 af[4];
    {
        const int row = wid * 16 + r15;
        #pragma unroll
        for (int ks = 0; ks < 4; ++ks) {
            const float4 w0 = *reinterpret_cast<const float4*>(W + row * CC + ks * 32 + q4 * 8);
            const float4 w1 = *reinterpret_cast<const float4*>(W + row * CC + ks * 32 + q4 * 8 + 4);
            short8 a;
            a[0] = f2bf(w0.x); a[1] = f2bf(w0.y); a[2] = f2bf(w0.z); a[3] = f2bf(w0.w);
            a[4] = f2bf(w1.x); a[5] = f2bf(w1.y); a[6] = f2bf(w1.z); a[7] = f2bf(w1.w);
            af[ks] = a;
        }
    }

    // ---- stage: transpose + cvt into swizzled bf16 tiles ----
    #pragma unroll
    for (int p = 0; p < 4; ++p) {
        const int c = cr + p * 32;
        const float* xs = reinterpret_cast<const float*>(&xv[p]);
        const float* zs = reinterpret_cast<const float*>(&zv[p]);
        #pragma unroll
        for (int j = 0; j < 4; ++j) {
            const int t  = tj + j;
            const int cs = swz(t, c);
            xt[t][cs] = f2bf(xs[j]);
            zt[t][cs] = f2bf(zs[j]);
        }
    }
    __syncthreads();

    // ---- MFMA: out tile [128 d][64 t]; wave w owns d in [16w, 16w+16) ----
    f32x4 aX[4], aZ[4];
    #pragma unroll
    for (int tt = 0; tt < 4; ++tt) { aX[tt] = (f32x4){0,0,0,0}; aZ[tt] = (f32x4){0,0,0,0}; }

    #pragma unroll
    for (int ks = 0; ks < 4; ++ks) {
        #pragma unroll
        for (int tt = 0; tt < 4; ++tt) {
            const int tr = tt * 16 + r15;
            const int cs = swz(tr, ks * 32 + q4 * 8);
            const short8 xa = *reinterpret_cast<const short8*>(&xt[tr][cs]);
            const short8 za = *reinterpret_cast<const short8*>(&zt[tr][cs]);
            aX[tt] = __builtin_amdgcn_mfma_f32_16x16x32_bf16(af[ks], xa, aX[tt], 0, 0, 0);
            aZ[tt] = __builtin_amdgcn_mfma_f32_16x16x32_bf16(af[ks], za, aZ[tt], 0, 0, 0);
        }
    }

    // ---- epilogue: D layout col(t)=lane&15, row(d)=q4*4+reg ----
    float lsum = 0.0f;
    #pragma unroll
    for (int rr = 0; rr < 4; ++rr) {
        const int d  = wid * 16 + q4 * 4 + rr;
        const float bl = blin[d];
        float* orow = out + 1 + (size_t)(b * CC + d) * TLEN + t0;
        #pragma unroll
        for (int tt = 0; tt < 4; ++tt) {
            const int tl = tt * 16 + r15;
            const int tg = t0 + tl;
            const float s  = cx * aX[tt][rr] + cz * aZ[tt][rr];
            const bool pm  = tg >= pl;
            const float ov = (pm ? s : 0.0f) + bl;
            const int cs   = swz(tl, d);
            const float w  = oms * bf2f((unsigned short)zt[tl][cs]);
            orow[tl] = ov + w;
            if (pm & (tg < xl)) {
                const float xf = bf2f((unsigned short)xt[tl][cs]);
                const float df = ov - (xf - w);
                lsum += df * df;
            }
        }
    }

    // ---- loss: wave reduce -> block reduce -> one atomicAdd ----
    #pragma unroll
    for (int off = 32; off >= 1; off >>= 1) lsum += __shfl_down(lsum, off);
    if (lane == 0) red[wid] = lsum;
    __syncthreads();
    if (tid == 0) {
        float s = 0.0f;
        #pragma unroll
        for (int w = 0; w < 8; ++w) s += red[w];
        atomicAdd(out, s / (1024.0f * (float)(xl - pl)));   // 1/(B*C*(xl-pl))
    }
}

extern "C" void kernel_launch(void* const* d_in, const int* in_sizes, int n_in,
                              void* d_out, int out_size, void* d_ws, size_t ws_size,
                              hipStream_t stream) {
    const float* x1    = (const float*)d_in[0];
    // d_in[1] = mu (unused), d_in[2] = style (unused)
    const float* tsm   = (const float*)d_in[3];
    const float* z     = (const float*)d_in[4];
    const float* W     = (const float*)d_in[5];
    const float* blin  = (const float*)d_in[6];
    const int*   xlens = (const int*)d_in[7];
    const int*   plens = (const int*)d_in[8];
    float* out = (float*)d_out;

    hipMemsetAsync(out, 0, sizeof(float), stream);   // zero the loss slot
    cfm_fused<<<NB, 512, 0, stream>>>(x1, tsm, z, W, blin, xlens, plens, out);
}

// Round 12
// 32.779 us; speedup vs baseline: 1.3322x; 1.3322x over previous
//
#include <hip/hip_runtime.h>
#include <hip/hip_bf16.h>

#define BB   8
#define CC   128
#define TLEN 8192
#define TBLK 128                     // t per block, single monolithic tile
#define NB   (BB * (TLEN / TBLK))    // 512 blocks = 2/CU

typedef __attribute__((ext_vector_type(8))) short short8;
typedef __attribute__((ext_vector_type(4))) float f32x4;

__device__ __forceinline__ short f2bf(float f) {
    union { float f; unsigned u; } v; v.f = f;
    return (short)((v.u + 0x7FFFu + ((v.u >> 16) & 1u)) >> 16);
}
__device__ __forceinline__ float bf2f(unsigned short h) {
    union { unsigned u; float f; } v; v.u = ((unsigned)h) << 16;
    return v.f;
}
// Row swizzle on c-octets: bijective per t-row, preserves 16B frag alignment.
__device__ __forceinline__ int swz(int t, int c) {
    return c ^ (((t ^ (t >> 3)) & 15) << 3);
}
// Forced-in-flight global load: asm output keeps all results live -> compiler
// cannot serialize into load->wait->use chains (it must allocate the VGPRs).
__device__ __forceinline__ f32x4 gload(const float* base, unsigned byteoff) {
    f32x4 r;
    asm volatile("global_load_dwordx4 %0, %1, %2"
                 : "=v"(r) : "v"(byteoff), "s"(base));
    return r;
}

__global__ __launch_bounds__(512, 4)   // 4 waves/EU = 2 blocks/CU
void cfm_fused(const float* __restrict__ x1, const float* __restrict__ tsm,
               const float* __restrict__ z, const float* __restrict__ W,
               const float* __restrict__ blin, const int* __restrict__ xlens,
               const int* __restrict__ plens, float* __restrict__ out)
{
    __shared__ short xt[TBLK][CC];   // bf16 [t][c], swizzled rows
    __shared__ short zt[TBLK][CC];
    __shared__ float red[8];

    const int bi = blockIdx.x;
    const int b  = bi & 7;           // XCD x serves batch x
    const int t0 = (bi >> 3) * TBLK;

    const int tid  = threadIdx.x;
    const int lane = tid & 63;
    const int wid  = tid >> 6;          // 0..7 = dtile
    const int r15  = lane & 15;
    const int q4   = lane >> 4;

    const float ts  = tsm[b];
    const int   pl  = plens[b];
    const int   xl  = xlens[b];
    const float oms = 0.999999f;        // 1 - sigma
    const float cz  = 1.0f - oms * ts;
    const float cx  = ts;

    // ---- W fragments first (L2/L3-hot on replays; compiler-managed waits) ----
    short8 af[4];
    {
        const int row = wid * 16 + r15;
        #pragma unroll
        for (int ks = 0; ks < 4; ++ks) {
            const float4 w0 = *reinterpret_cast<const float4*>(W + row * CC + ks * 32 + q4 * 8);
            const float4 w1 = *reinterpret_cast<const float4*>(W + row * CC + ks * 32 + q4 * 8 + 4);
            short8 a;
            a[0] = f2bf(w0.x); a[1] = f2bf(w0.y); a[2] = f2bf(w0.z); a[3] = f2bf(w0.w);
            a[4] = f2bf(w1.x); a[5] = f2bf(w1.y); a[6] = f2bf(w1.z); a[7] = f2bf(w1.w);
            af[ks] = a;
        }
    }

    // ---- 16 forced-in-flight dwordx4 loads (512B/row spans) ----
    const int tpart = (tid & 31) * 4;   // local t base
    const int c0    = tid >> 5;         // 0..15
    const size_t rowb = (size_t)b * CC * TLEN + (size_t)t0 + tpart;

    __builtin_amdgcn_sched_barrier(0);
    f32x4 xv[8], zv[8];
    #pragma unroll
    for (int p = 0; p < 8; ++p)
        xv[p] = gload(x1, (unsigned)((rowb + (size_t)(c0 + p * 16) * TLEN) * 4));
    #pragma unroll
    for (int p = 0; p < 8; ++p)
        zv[p] = gload(z, (unsigned)((rowb + (size_t)(c0 + p * 16) * TLEN) * 4));
    __builtin_amdgcn_sched_barrier(0);
    asm volatile("s_waitcnt vmcnt(0)" ::: "memory");
    __builtin_amdgcn_sched_barrier(0);

    // ---- stage: transpose + cvt into swizzled bf16 tiles ----
    #pragma unroll
    for (int p = 0; p < 8; ++p) {
        const int c = c0 + p * 16;
        #pragma unroll
        for (int j = 0; j < 4; ++j) {
            const int t  = tpart + j;
            const int cs = swz(t, c);
            xt[t][cs] = f2bf(xv[p][j]);
            zt[t][cs] = f2bf(zv[p][j]);
        }
    }
    __syncthreads();

    // ---- MFMA: out tile [128 d][128 t]; wave w owns d in [16w, 16w+16) ----
    f32x4 aX[8], aZ[8];
    #pragma unroll
    for (int tt = 0; tt < 8; ++tt) { aX[tt] = (f32x4){0,0,0,0}; aZ[tt] = (f32x4){0,0,0,0}; }

    #pragma unroll
    for (int ks = 0; ks < 4; ++ks) {
        #pragma unroll
        for (int tt = 0; tt < 8; ++tt) {
            const int tr = tt * 16 + r15;
            const int cs = swz(tr, ks * 32 + q4 * 8);
            const short8 xa = *reinterpret_cast<const short8*>(&xt[tr][cs]);
            const short8 za = *reinterpret_cast<const short8*>(&zt[tr][cs]);
            aX[tt] = __builtin_amdgcn_mfma_f32_16x16x32_bf16(af[ks], xa, aX[tt], 0, 0, 0);
            aZ[tt] = __builtin_amdgcn_mfma_f32_16x16x32_bf16(af[ks], za, aZ[tt], 0, 0, 0);
        }
    }

    // ---- epilogue: D layout col(t)=lane&15, row(d)=q4*4+reg ----
    float lsum = 0.0f;
    #pragma unroll
    for (int rr = 0; rr < 4; ++rr) {
        const int d  = wid * 16 + q4 * 4 + rr;
        const float bl = blin[d];
        float* orow = out + 1 + (size_t)(b * CC + d) * TLEN + t0;
        #pragma unroll
        for (int tt = 0; tt < 8; ++tt) {
            const int tl = tt * 16 + r15;
            const int tg = t0 + tl;
            const float s  = cx * aX[tt][rr] + cz * aZ[tt][rr];
            const bool pm  = tg >= pl;
            const float ov = (pm ? s : 0.0f) + bl;
            const int cs   = swz(tl, d);
            const float w  = oms * bf2f((unsigned short)zt[tl][cs]);
            orow[tl] = ov + w;
            if (pm & (tg < xl)) {
                const float xf = bf2f((unsigned short)xt[tl][cs]);
                const float df = ov - (xf - w);
                lsum += df * df;
            }
        }
    }

    // ---- loss: wave reduce -> block reduce -> one atomicAdd ----
    #pragma unroll
    for (int off = 32; off >= 1; off >>= 1) lsum += __shfl_down(lsum, off);
    if (lane == 0) red[wid] = lsum;
    __syncthreads();
    if (tid == 0) {
        float s = 0.0f;
        #pragma unroll
        for (int w = 0; w < 8; ++w) s += red[w];
        atomicAdd(out, s / (1024.0f * (float)(xl - pl)));   // 1/(B*C*(xl-pl))
    }
}

extern "C" void kernel_launch(void* const* d_in, const int* in_sizes, int n_in,
                              void* d_out, int out_size, void* d_ws, size_t ws_size,
                              hipStream_t stream) {
    const float* x1    = (const float*)d_in[0];
    // d_in[1] = mu (unused), d_in[2] = style (unused)
    const float* tsm   = (const float*)d_in[3];
    const float* z     = (const float*)d_in[4];
    const float* W     = (const float*)d_in[5];
    const float* blin  = (const float*)d_in[6];
    const int*   xlens = (const int*)d_in[7];
    const int*   plens = (const int*)d_in[8];
    float* out = (float*)d_out;

    hipMemsetAsync(out, 0, sizeof(float), stream);   // zero the loss slot
    cfm_fused<<<NB, 512, 0, stream>>>(x1, tsm, z, W, blin, xlens, plens, out);
}

// Round 13
// 30.452 us; speedup vs baseline: 1.4340x; 1.0764x over previous
//
#include <hip/hip_runtime.h>
#include <hip/hip_bf16.h>

#define BB    8
#define CC    128
#define TLEN  8192
#define TT    32                      // t per tile
#define TILES 4                       // tiles per block
#define TSPAN (TT * TILES)            // 128 t per block
#define NB    (BB * (TLEN / TSPAN))   // 512 blocks = 2/CU

typedef __attribute__((ext_vector_type(8))) short short8;
typedef __attribute__((ext_vector_type(4))) float f32x4;

__device__ __forceinline__ short f2bf(float f) {
    union { float f; unsigned u; } v; v.f = f;
    return (short)((v.u + 0x7FFFu + ((v.u >> 16) & 1u)) >> 16);
}
// bf16 y-tile swizzle (c-octets XOR'd by t-hash) — verified R5..R12
__device__ __forceinline__ int swzY(int t, int c) {
    return c ^ (((t ^ (t >> 3)) & 15) << 3);
}
// f32 staging-tile swizzle: XOR float-index bits 2-4 by c — spreads banks for
// repack quads (2-way max) and epilogue scalars (2-way max). DMA-compatible:
// dest stays linear; the SOURCE t-offset is pre-swizzled per lane (m201 rule).
__device__ __forceinline__ int sfz(int c) {
    return ((c & 3) << 3) | (((c >> 2) & 1) << 2);
}

#define VMWAIT(N) asm volatile("s_waitcnt vmcnt(" #N ")" ::: "memory")

__device__ __forceinline__ void bar_lgkm() {
    asm volatile("s_waitcnt lgkmcnt(0)" ::: "memory");
    __builtin_amdgcn_s_barrier();
}

typedef __attribute__((address_space(1))) const unsigned GU;
typedef __attribute__((address_space(3))) unsigned LU;
__device__ __forceinline__ void glds16(const float* g, const float* l) {
    __builtin_amdgcn_global_load_lds((GU*)g, (LU*)l, 16, 0, 0);
}

__global__ __launch_bounds__(512, 4)
void cfm_fused(const float* __restrict__ x1, const float* __restrict__ tsm,
               const float* __restrict__ z, const float* __restrict__ W,
               const float* __restrict__ blin, const int* __restrict__ xlens,
               const int* __restrict__ plens, float* __restrict__ out)
{
    __shared__ float xf[2][CC * TT];   // f32 [c][32t] (sfz-swizzled), dbuf, 32 KB
    __shared__ float zf[2][CC * TT];   // 32 KB
    __shared__ short ybf[TT][CC];      // bf16 y tile [t][c] (swzY), 8 KB
    __shared__ float red[8];

    const int bi    = blockIdx.x;
    const int b     = bi & 7;
    const int tbase = (bi >> 3) * TSPAN;

    const int tid  = threadIdx.x;
    const int lane = tid & 63;
    const int wid  = tid >> 6;          // 0..7; wave owns d in [16w,16w+16)
    const int r15  = lane & 15;
    const int q4   = lane >> 4;

    const float ts  = tsm[b];
    const int   pl  = plens[b];
    const int   xl  = xlens[b];
    const float oms = 0.999999f;        // 1 - sigma
    const float cz  = 1.0f - oms * ts;
    const float cx  = ts;

    // ---- prologue vmem (all OLDER than stage DMAs): W frags + bias regs ----
    short8 af[4];
    {
        const int row = wid * 16 + r15;
        #pragma unroll
        for (int ks = 0; ks < 4; ++ks) {
            const float4 w0 = *reinterpret_cast<const float4*>(W + row * CC + ks * 32 + q4 * 8);
            const float4 w1 = *reinterpret_cast<const float4*>(W + row * CC + ks * 32 + q4 * 8 + 4);
            short8 a;
            a[0] = f2bf(w0.x); a[1] = f2bf(w0.y); a[2] = f2bf(w0.z); a[3] = f2bf(w0.w);
            a[4] = f2bf(w1.x); a[5] = f2bf(w1.y); a[6] = f2bf(w1.z); a[7] = f2bf(w1.w);
            af[ks] = a;
        }
    }
    float bl[4];
    #pragma unroll
    for (int rr = 0; rr < 4; ++rr) bl[rr] = blin[wid * 16 + q4 * 4 + rr];

    // ---- DMA staging geometry: chunk = [8c][32t] = 1KB = one wave-instr ----
    // lane l -> c = cbase + (l>>3), t = ((l&7)*4) ^ sfz(l>>3)  (inverse-swz src)
    const int cl  = lane >> 3;
    const int tsw = ((lane & 7) * 4) ^ sfz(cl);
    const size_t gB = (size_t)b * CC * TLEN;
    const int ca = wid * 16, cb = ca + 8;   // this wave's two c-chunks

    // 4 glds per wave per tile (x:2, z:2)
    #define STAGE(buf, t0k) do {                                              \
        glds16(x1 + gB + (size_t)(ca + cl) * TLEN + (t0k) + tsw, &xf[buf][ca * TT]); \
        glds16(x1 + gB + (size_t)(cb + cl) * TLEN + (t0k) + tsw, &xf[buf][cb * TT]); \
        glds16(z  + gB + (size_t)(ca + cl) * TLEN + (t0k) + tsw, &zf[buf][ca * TT]); \
        glds16(z  + gB + (size_t)(cb + cl) * TLEN + (t0k) + tsw, &zf[buf][cb * TT]); \
    } while (0)

    // ---- repack: f32 LDS -> masked/blended y bf16 tile ----
    const int rc  = tid >> 2;            // c row 0..127
    const int tg8 = (tid & 3) * 8;       // 8 t per thread
    const int fidx = (rc * TT + tg8) ^ sfz(rc);

    #define REPACK(buf, t0k) do {                                             \
        const f32x4 xa = *reinterpret_cast<const f32x4*>(&xf[buf][fidx]);     \
        const f32x4 xb = *reinterpret_cast<const f32x4*>(&xf[buf][fidx ^ 4]); \
        const f32x4 za = *reinterpret_cast<const f32x4*>(&zf[buf][fidx]);     \
        const f32x4 zb = *reinterpret_cast<const f32x4*>(&zf[buf][fidx ^ 4]); \
        _Pragma("unroll")                                                     \
        for (int j = 0; j < 4; ++j) {                                         \
            const int t0j = tg8 + j, t1j = tg8 + 4 + j;                       \
            const float y0 = ((t0k) + t0j < pl) ? 0.0f : cz * za[j] + cx * xa[j]; \
            const float y1 = ((t0k) + t1j < pl) ? 0.0f : cz * zb[j] + cx * xb[j]; \
            ybf[t0j][swzY(t0j, rc)] = f2bf(y0);                               \
            ybf[t1j][swzY(t1j, rc)] = f2bf(y1);                               \
        }                                                                     \
    } while (0)

    // ---- MFMA + epilogue (8 stores/thread -> counts in vmcnt formula) ----
    float lsum = 0.0f;
    #define COMPUTE(buf, t0k) do {                                            \
        f32x4 acc[2];                                                         \
        acc[0] = (f32x4){0,0,0,0}; acc[1] = (f32x4){0,0,0,0};                 \
        _Pragma("unroll")                                                     \
        for (int ks = 0; ks < 4; ++ks) {                                      \
            _Pragma("unroll")                                                 \
            for (int tt = 0; tt < 2; ++tt) {                                  \
                const int tr = tt * 16 + r15;                                 \
                const short8 ya = *reinterpret_cast<const short8*>(           \
                    &ybf[tr][swzY(tr, ks * 32 + q4 * 8)]);                    \
                acc[tt] = __builtin_amdgcn_mfma_f32_16x16x32_bf16(af[ks], ya, acc[tt], 0, 0, 0); \
            }                                                                 \
        }                                                                     \
        _Pragma("unroll")                                                     \
        for (int rr = 0; rr < 4; ++rr) {                                      \
            const int d = wid * 16 + q4 * 4 + rr;                             \
            float* orow = out + 1 + (size_t)(b * CC + d) * TLEN + (t0k);      \
            _Pragma("unroll")                                                 \
            for (int tt = 0; tt < 2; ++tt) {                                  \
                const int tl = tt * 16 + r15;                                 \
                const int fi = (d * TT + tl) ^ sfz(d);                        \
                const float zfv = zf[buf][fi];                                \
                const float xfv = xf[buf][fi];                                \
                const float ov  = acc[tt][rr] + bl[rr];                       \
                const float o2  = ov + oms * zfv;                             \
                orow[tl] = o2;                                                \
                const int tgl = (t0k) + tl;                                   \
                if ((tgl >= pl) & (tgl < xl)) { const float df = o2 - xfv; lsum += df * df; } \
            }                                                                 \
        }                                                                     \
    } while (0)

    // ================= pipelined 4-tile loop =================
    STAGE(0, tbase);            // 4 instr in flight
    STAGE(1, tbase + TT);       // 8

    // tile 0: wait S0 (allow S1=4 newer)
    VMWAIT(4);  __builtin_amdgcn_sched_barrier(0); bar_lgkm();
    REPACK(0, tbase);                       bar_lgkm();
    COMPUTE(0, tbase);                      bar_lgkm();
    STAGE(0, tbase + 2 * TT);

    // tile 1: wait S1 (allow st0=8 + S2=4 newer)
    VMWAIT(12); __builtin_amdgcn_sched_barrier(0); bar_lgkm();
    REPACK(1, tbase + TT);                  bar_lgkm();
    COMPUTE(1, tbase + TT);                 bar_lgkm();
    STAGE(1, tbase + 3 * TT);

    // tile 2: wait S2 (allow st1=8 + S3=4 newer)
    VMWAIT(12); __builtin_amdgcn_sched_barrier(0); bar_lgkm();
    REPACK(0, tbase + 2 * TT);              bar_lgkm();
    COMPUTE(0, tbase + 2 * TT);             bar_lgkm();

    // tile 3: wait S3 (allow st2=8 newer)
    VMWAIT(8);  __builtin_amdgcn_sched_barrier(0); bar_lgkm();
    REPACK(1, tbase + 3 * TT);              bar_lgkm();
    COMPUTE(1, tbase + 3 * TT);

    // ---- loss: wave reduce -> block reduce -> one atomicAdd ----
    #pragma unroll
    for (int off = 32; off >= 1; off >>= 1) lsum += __shfl_down(lsum, off);
    if (lane == 0) red[wid] = lsum;
    __syncthreads();
    if (tid == 0) {
        float s = 0.0f;
        #pragma unroll
        for (int w = 0; w < 8; ++w) s += red[w];
        atomicAdd(out, s / (1024.0f * (float)(xl - pl)));   // 1/(B*C*(xl-pl))
    }
}

extern "C" void kernel_launch(void* const* d_in, const int* in_sizes, int n_in,
                              void* d_out, int out_size, void* d_ws, size_t ws_size,
                              hipStream_t stream) {
    const float* x1    = (const float*)d_in[0];
    // d_in[1] = mu (unused), d_in[2] = style (unused)
    const float* tsm   = (const float*)d_in[3];
    const float* z     = (const float*)d_in[4];
    const float* W     = (const float*)d_in[5];
    const float* blin  = (const float*)d_in[6];
    const int*   xlens = (const int*)d_in[7];
    const int*   plens = (const int*)d_in[8];
    float* out = (float*)d_out;

    hipMemsetAsync(out, 0, sizeof(float), stream);   // zero the loss slot
    cfm_fused<<<NB, 512, 0, stream>>>(x1, tsm, z, W, blin, xlens, plens, out);
}